// Round 1
// baseline (184.917 us; speedup 1.0000x reference)
//
#include <hip/hip_runtime.h>
#include <hip/hip_bf16.h>
#include <math.h>

// Problem constants
#define B_ 512
#define L_ 256
#define D_ 256
#define V_ 100000
#define O_ 1000

typedef __attribute__((ext_vector_type(8))) short short8;
typedef __attribute__((ext_vector_type(4))) float f32x4;

static __device__ __forceinline__ unsigned short f2bf(float f) {
    union { float f; unsigned u; } v; v.f = f;
    unsigned r = v.u + 0x7FFFu + ((v.u >> 16) & 1u);   // RNE (inputs are finite)
    return (unsigned short)(r >> 16);
}
static __device__ __forceinline__ float bf2f(unsigned short u) {
    union { unsigned u; float f; } v; v.u = ((unsigned)u) << 16;
    return v.f;
}

// ---------------- Kernel 1: embedding gather + cast to bf16 ----------------
// E[b*L + l][d] = bf16(emb[tok[b*L+l]][d]).  Each thread: 8 elements (32B read, 16B write).
__global__ __launch_bounds__(256) void k_gather(const int* __restrict__ tok,
                                                const float* __restrict__ emb,
                                                unsigned short* __restrict__ E) {
    int gid = blockIdx.x * 256 + threadIdx.x;     // 4,194,304 threads
    int row = gid >> 5;                            // 32 threads per 256-elem row
    int off = (gid & 31) << 3;
    int t = tok[row];
    const float4* src = (const float4*)(emb + (size_t)t * D_ + off);
    float4 a = src[0], b = src[1];
    short8 o;
    o[0] = (short)f2bf(a.x); o[1] = (short)f2bf(a.y);
    o[2] = (short)f2bf(a.z); o[3] = (short)f2bf(a.w);
    o[4] = (short)f2bf(b.x); o[5] = (short)f2bf(b.y);
    o[6] = (short)f2bf(b.z); o[7] = (short)f2bf(b.w);
    *(short8*)(E + (size_t)row * D_ + off) = o;
}

// ---------------- Kernel 1b: W_b transpose + cast: Wt[e][d] = bf16(W_b[d][e]) ----------------
__global__ __launch_bounds__(256) void k_wt(const float* __restrict__ Wb,
                                            unsigned short* __restrict__ Wt) {
    int i = blockIdx.x * 256 + threadIdx.x;       // 65536
    int d = i >> 8, e = i & 255;
    Wt[e * 256 + d] = f2bf(Wb[i]);
}

// ---------------- Kernel 2: F = E * W_b  (bf16 MFMA, fp32 accum, store bf16) ----------------
// M = B*L = 131072, N = 256, K = 256.  Block = 256 thr (4 waves, 2x2), tile 128x128.
// A-frag: lane reads E[row][k0+8*gp + i]  (16B contiguous)
// B-frag: lane reads Wt[col][k0+8*gp + i] (16B contiguous; Wt is W_b^T so this is W_b[k][col])
__global__ __launch_bounds__(256) void k_gemm_F(const unsigned short* __restrict__ E,
                                                const unsigned short* __restrict__ Wt,
                                                unsigned short* __restrict__ F) {
    int wid = threadIdx.x >> 6, ln = threadIdx.x & 63;
    int wr = wid >> 1, wc = wid & 1;
    int rBase = blockIdx.x * 128 + wr * 64;
    int cBase = blockIdx.y * 128 + wc * 64;
    int l16 = ln & 15, gp = ln >> 4;
    f32x4 acc[4][4] = {};
    for (int k0 = 0; k0 < 256; k0 += 32) {
        int kk = k0 + gp * 8;
        short8 a[4], b[4];
#pragma unroll
        for (int rf = 0; rf < 4; rf++)
            a[rf] = *(const short8*)(E + (size_t)(rBase + rf * 16 + l16) * 256 + kk);
#pragma unroll
        for (int cf = 0; cf < 4; cf++)
            b[cf] = *(const short8*)(Wt + (size_t)(cBase + cf * 16 + l16) * 256 + kk);
#pragma unroll
        for (int rf = 0; rf < 4; rf++)
#pragma unroll
            for (int cf = 0; cf < 4; cf++)
                acc[rf][cf] = __builtin_amdgcn_mfma_f32_16x16x32_bf16(a[rf], b[cf], acc[rf][cf], 0, 0, 0);
    }
#pragma unroll
    for (int rf = 0; rf < 4; rf++)
#pragma unroll
        for (int cf = 0; cf < 4; cf++)
#pragma unroll
            for (int r = 0; r < 4; r++) {
                int row = rBase + rf * 16 + gp * 4 + r;
                int col = cBase + cf * 16 + l16;
                F[(size_t)row * 256 + col] = f2bf(acc[rf][cf][r]);
            }
}

// ---------------- Kernel 3: per-batch  rowmax(F[b]*E[b]^T) -> tanh -> softmax -> f_w ----------------
// One block per batch (256 thr, 4 waves). Wave w owns G rows [w*64, w*64+64).
// ct loop stages E rows [64ct,64ct+64) (the G columns) into swizzled LDS.
__global__ __launch_bounds__(256) void k_attn(const unsigned short* __restrict__ E,
                                              const unsigned short* __restrict__ F,
                                              float* __restrict__ fw) {
    __shared__ unsigned short Es[64 * 256];   // 32KB, XOR-swizzled rows
    __shared__ float red[256];
    __shared__ float scratch[8];
    int b = blockIdx.x;
    int tid = threadIdx.x;
    int wid = tid >> 6, ln = tid & 63;
    int l16 = ln & 15, gp = ln >> 4;
    const unsigned short* Eb = E + (size_t)b * 256 * 256;
    const unsigned short* Fb = F + (size_t)b * 256 * 256;
    int rowA = wid * 64;

    float rmax[16];
#pragma unroll
    for (int i = 0; i < 16; i++) rmax[i] = -1e30f;

    for (int ct = 0; ct < 4; ct++) {
        __syncthreads();
        // stage 64 rows x 256 cols bf16 (32KB) with byte ^= (row&7)<<4 swizzle
#pragma unroll
        for (int it = 0; it < 8; it++) {
            int c = it * 256 + tid;           // 2048 16B-chunks
            int r = c >> 5, c16 = c & 31;
            short8 v = *(const short8*)(Eb + (((64 * ct + r) << 8) + (c16 << 3)));
            int byte = r * 512 + ((c16 * 16) ^ ((r & 7) << 4));
            *(short8*)((char*)Es + byte) = v;
        }
        __syncthreads();

        f32x4 acc[4][4] = {};
        for (int k0 = 0; k0 < 256; k0 += 32) {
            int kk = k0 + gp * 8;
            short8 a[4];
#pragma unroll
            for (int rf = 0; rf < 4; rf++)
                a[rf] = *(const short8*)(Fb + ((rowA + rf * 16 + l16) << 8) + kk);
            short8 bb[4];
#pragma unroll
            for (int cf = 0; cf < 4; cf++) {
                int r = cf * 16 + l16;        // local column index = Es row
                int byte = r * 512 + (((kk * 2)) ^ ((r & 7) << 4));
                bb[cf] = *(const short8*)((const char*)Es + byte);
            }
#pragma unroll
            for (int rf = 0; rf < 4; rf++)
#pragma unroll
                for (int cf = 0; cf < 4; cf++)
                    acc[rf][cf] = __builtin_amdgcn_mfma_f32_16x16x32_bf16(a[rf], bb[cf], acc[rf][cf], 0, 0, 0);
        }
        // update per-lane row maxima (over this 64-col tile)
#pragma unroll
        for (int rf = 0; rf < 4; rf++)
#pragma unroll
            for (int r = 0; r < 4; r++) {
                float m = fmaxf(fmaxf(acc[rf][0][r], acc[rf][1][r]),
                                fmaxf(acc[rf][2][r], acc[rf][3][r]));
                rmax[rf * 4 + r] = fmaxf(rmax[rf * 4 + r], m);
            }
    }
    // reduce across the 16 lanes (same gp group) holding different columns of a row
#pragma unroll
    for (int i = 0; i < 16; i++) {
        float v = rmax[i];
        v = fmaxf(v, __shfl_xor(v, 1));
        v = fmaxf(v, __shfl_xor(v, 2));
        v = fmaxf(v, __shfl_xor(v, 4));
        v = fmaxf(v, __shfl_xor(v, 8));
        rmax[i] = v;
    }
    if (l16 == 0) {
#pragma unroll
        for (int rf = 0; rf < 4; rf++)
#pragma unroll
            for (int r = 0; r < 4; r++)
                red[rowA + rf * 16 + gp * 4 + r] = rmax[rf * 4 + r];
    }
    __syncthreads();

    // softmax over the 256 row-maxima (tanh applied after max: tanh is monotonic)
    float x = tanhf(red[tid]);
    float m = x;
#pragma unroll
    for (int s = 1; s < 64; s <<= 1) m = fmaxf(m, __shfl_xor(m, s));
    if (ln == 0) scratch[wid] = m;
    __syncthreads();
    m = fmaxf(fmaxf(scratch[0], scratch[1]), fmaxf(scratch[2], scratch[3]));
    float e = expf(x - m);
    float ssum = e;
#pragma unroll
    for (int s = 1; s < 64; s <<= 1) ssum += __shfl_xor(ssum, s);
    if (ln == 0) scratch[4 + wid] = ssum;
    __syncthreads();
    ssum = (scratch[4] + scratch[5]) + (scratch[6] + scratch[7]);
    float aq = e / ssum;
    __syncthreads();
    red[tid] = aq;
    __syncthreads();

    // f_w[d] = sum_l a[l] * E[b][l][d]   (coalesced row reads from global, L2-hot)
    float f = 0.f;
    for (int l = 0; l < 256; l++)
        f += red[l] * bf2f(Eb[l * 256 + tid]);
    fw[b * 256 + tid] = f;
}

// ---------------- Kernel 4: out = f_w @ lin_w^T + lin_b  (fp32 tiled GEMM) ----------------
// M=512, N=1000, K=256. Tile 64x64, 256 thr, 4x4 per thread.
__global__ __launch_bounds__(256) void k_out(const float* __restrict__ fw,
                                             const float* __restrict__ lw,
                                             const float* __restrict__ lb,
                                             float* __restrict__ out) {
    __shared__ float As[64][65];
    __shared__ float Bs[64][65];
    int tx = threadIdx.x & 15, ty = threadIdx.x >> 4;
    int r0 = blockIdx.y * 64, n0 = blockIdx.x * 64;
    float acc[4][4] = {};
    for (int k0 = 0; k0 < 256; k0 += 64) {
        __syncthreads();
#pragma unroll
        for (int it = 0; it < 16; it++) {
            int idx = it * 256 + threadIdx.x;
            int i = idx >> 6, k = idx & 63;
            As[i][k] = fw[(r0 + i) * 256 + k0 + k];
            int n = n0 + i;
            Bs[k][i] = (n < O_) ? lw[(size_t)n * 256 + k0 + k] : 0.f;
        }
        __syncthreads();
#pragma unroll
        for (int k = 0; k < 64; k++) {
            float a[4], bb[4];
#pragma unroll
            for (int i = 0; i < 4; i++) a[i] = As[ty * 4 + i][k];
#pragma unroll
            for (int j = 0; j < 4; j++) bb[j] = Bs[k][tx * 4 + j];
#pragma unroll
            for (int i = 0; i < 4; i++)
#pragma unroll
                for (int j = 0; j < 4; j++) acc[i][j] += a[i] * bb[j];
        }
    }
#pragma unroll
    for (int i = 0; i < 4; i++)
#pragma unroll
        for (int j = 0; j < 4; j++) {
            int n = n0 + tx * 4 + j;
            if (n < O_) out[(size_t)(r0 + ty * 4 + i) * O_ + n] = acc[i][j] + lb[n];
        }
}

extern "C" void kernel_launch(void* const* d_in, const int* in_sizes, int n_in,
                              void* d_out, int out_size, void* d_ws, size_t ws_size,
                              hipStream_t stream) {
    const int* tok = (const int*)d_in[0];
    const float* emb = (const float*)d_in[1];
    const float* Wb = (const float*)d_in[2];
    const float* lw = (const float*)d_in[3];
    const float* lb = (const float*)d_in[4];
    float* out = (float*)d_out;

    char* ws = (char*)d_ws;
    unsigned short* E  = (unsigned short*)(ws);                 // 67,108,864 B
    unsigned short* F  = (unsigned short*)(ws + 67108864);      // 67,108,864 B
    unsigned short* Wt = (unsigned short*)(ws + 134217728);     //    131,072 B
    float*          fwp = (float*)(ws + 134348800);             //    524,288 B

    hipLaunchKernelGGL(k_gather, dim3(16384), dim3(256), 0, stream, tok, emb, E);
    hipLaunchKernelGGL(k_wt,     dim3(256),   dim3(256), 0, stream, Wb, Wt);
    hipLaunchKernelGGL(k_gemm_F, dim3(1024, 2), dim3(256), 0, stream, E, Wt, F);
    hipLaunchKernelGGL(k_attn,   dim3(512),   dim3(256), 0, stream, E, F, fwp);
    hipLaunchKernelGGL(k_out,    dim3(16, 8), dim3(256), 0, stream, fwp, lw, lb, out);
}

// Round 2
// 156.972 us; speedup vs baseline: 1.1780x; 1.1780x over previous
//
#include <hip/hip_runtime.h>
#include <hip/hip_bf16.h>
#include <math.h>

// Problem constants
#define B_ 512
#define L_ 256
#define D_ 256
#define V_ 100000
#define O_ 1000

typedef __attribute__((ext_vector_type(8))) short short8;
typedef __attribute__((ext_vector_type(4))) float f32x4;

static __device__ __forceinline__ unsigned short f2bf(float f) {
    union { float f; unsigned u; } v; v.f = f;
    unsigned r = v.u + 0x7FFFu + ((v.u >> 16) & 1u);   // RNE (inputs are finite)
    return (unsigned short)(r >> 16);
}
static __device__ __forceinline__ float bf2f(unsigned short u) {
    union { unsigned u; float f; } v; v.u = ((unsigned)u) << 16;
    return v.f;
}

// ---------------- Kernel 1: embedding gather + cast to bf16 ----------------
__global__ __launch_bounds__(256) void k_gather(const int* __restrict__ tok,
                                                const float* __restrict__ emb,
                                                unsigned short* __restrict__ E) {
    int gid = blockIdx.x * 256 + threadIdx.x;     // 4,194,304 threads
    int row = gid >> 5;                            // 32 threads per 256-elem row
    int off = (gid & 31) << 3;
    int t = tok[row];
    const float4* src = (const float4*)(emb + (size_t)t * D_ + off);
    float4 a = src[0], b = src[1];
    short8 o;
    o[0] = (short)f2bf(a.x); o[1] = (short)f2bf(a.y);
    o[2] = (short)f2bf(a.z); o[3] = (short)f2bf(a.w);
    o[4] = (short)f2bf(b.x); o[5] = (short)f2bf(b.y);
    o[6] = (short)f2bf(b.z); o[7] = (short)f2bf(b.w);
    *(short8*)(E + (size_t)row * D_ + off) = o;
}

// ---------------- Kernel 1b: W_b cast to bf16 (row-major, no transpose) ----------------
__global__ __launch_bounds__(256) void k_wt(const float* __restrict__ Wb,
                                            unsigned short* __restrict__ Wbf) {
    int i = blockIdx.x * 256 + threadIdx.x;       // 65536
    Wbf[i] = f2bf(Wb[i]);
}

// ---------------- Kernel 2 (fused): per-batch G = E_b * W_b * E_b^T ----------------
// One block per batch, 512 threads (8 waves), 1 block/CU (128KB+ LDS).
// Phase 1: H'[i][j] = sum_e Wb[i,e]*E_b[j,e]  -> store bf16 TRANSPOSED: Ht[j][i],
//          XOR-swizzled (byte ^= (row&7)<<4 within 512B rows) for conflict-free phase-2 reads.
// Phase 2: G[l][m] = sum_d E_b[l,d]*Ht[m,d]; rowmax over m on the fly.
// Then tanh (monotone: tanh(max)=max(tanh)) -> softmax over L -> f_w = a^T E_b.
__global__ __launch_bounds__(512, 2) void k_attn(const unsigned short* __restrict__ E,
                                                 const unsigned short* __restrict__ Wbf,
                                                 float* __restrict__ fw) {
    __shared__ char HtS[131072];          // 256 rows x 512B (bf16), swizzled
    __shared__ float red2[2][256];
    __shared__ float scratch[16];
    int b = blockIdx.x;
    int tid = threadIdx.x;
    int wid = tid >> 6, ln = tid & 63;
    int l16 = ln & 15, gp = ln >> 4;
    const unsigned short* Eb = E + ((size_t)b << 16);

    // ---- Phase 1 ----
    {
        int i0 = (wid >> 2) * 64;          // Wb-row block (+128 for second)
        int j0 = (wid & 3) * 64;           // E-row block
        f32x4 acc[2][4][4] = {};
        for (int k0 = 0; k0 < 256; k0 += 32) {
            int kk = k0 + gp * 8;
            short8 bfr[4];
#pragma unroll
            for (int cf = 0; cf < 4; cf++)
                bfr[cf] = *(const short8*)(Eb + ((j0 + cf * 16 + l16) << 8) + kk);
            short8 afr[2][4];
#pragma unroll
            for (int ri = 0; ri < 2; ri++)
#pragma unroll
                for (int rf = 0; rf < 4; rf++)
                    afr[ri][rf] = *(const short8*)(Wbf + ((i0 + ri * 128 + rf * 16 + l16) << 8) + kk);
#pragma unroll
            for (int ri = 0; ri < 2; ri++)
#pragma unroll
                for (int rf = 0; rf < 4; rf++)
#pragma unroll
                    for (int cf = 0; cf < 4; cf++)
                        acc[ri][rf][cf] = __builtin_amdgcn_mfma_f32_16x16x32_bf16(
                            afr[ri][rf], bfr[cf], acc[ri][rf][cf], 0, 0, 0);
        }
        // write H' transposed into Ht (bf16), 8B per lane per tile
#pragma unroll
        for (int ri = 0; ri < 2; ri++)
#pragma unroll
            for (int rf = 0; rf < 4; rf++)
#pragma unroll
                for (int cf = 0; cf < 4; cf++) {
                    int i = i0 + ri * 128 + rf * 16 + gp * 4;   // H' row -> Ht col
                    int j = j0 + cf * 16 + l16;                 // H' col -> Ht row
                    unsigned long long pk;
                    unsigned short* p = (unsigned short*)&pk;
                    p[0] = f2bf(acc[ri][rf][cf][0]);
                    p[1] = f2bf(acc[ri][rf][cf][1]);
                    p[2] = f2bf(acc[ri][rf][cf][2]);
                    p[3] = f2bf(acc[ri][rf][cf][3]);
                    int byte = j * 512 + ((i * 2) ^ ((j & 7) << 4));
                    *(unsigned long long*)(HtS + byte) = pk;
                }
    }
    __syncthreads();

    // ---- Phase 2: G rowmax ----
    {
        int l0 = (wid & 3) * 64;           // G rows
        int m0 = (wid >> 2) * 128;         // G cols (128 wide = 8 col-frags)
        f32x4 acc[4][8] = {};
        for (int k0 = 0; k0 < 256; k0 += 32) {
            int kk = k0 + gp * 8;
            short8 a[4];
#pragma unroll
            for (int rf = 0; rf < 4; rf++)
                a[rf] = *(const short8*)(Eb + ((l0 + rf * 16 + l16) << 8) + kk);
            short8 bb[8];
#pragma unroll
            for (int cf = 0; cf < 8; cf++) {
                int m = m0 + cf * 16 + l16;
                int byte = m * 512 + ((kk * 2) ^ ((m & 7) << 4));
                bb[cf] = *(const short8*)(HtS + byte);
            }
#pragma unroll
            for (int rf = 0; rf < 4; rf++)
#pragma unroll
                for (int cf = 0; cf < 8; cf++)
                    acc[rf][cf] = __builtin_amdgcn_mfma_f32_16x16x32_bf16(
                        a[rf], bb[cf], acc[rf][cf], 0, 0, 0);
        }
#pragma unroll
        for (int rf = 0; rf < 4; rf++)
#pragma unroll
            for (int r = 0; r < 4; r++) {
                float mx = acc[rf][0][r];
#pragma unroll
                for (int cf = 1; cf < 8; cf++) mx = fmaxf(mx, acc[rf][cf][r]);
                mx = fmaxf(mx, __shfl_xor(mx, 1));
                mx = fmaxf(mx, __shfl_xor(mx, 2));
                mx = fmaxf(mx, __shfl_xor(mx, 4));
                mx = fmaxf(mx, __shfl_xor(mx, 8));
                if (l16 == 0)
                    red2[wid >> 2][l0 + rf * 16 + gp * 4 + r] = mx;
            }
    }
    __syncthreads();

    // ---- tanh + softmax over the 256 row-maxima ----
    float x = -1e30f;
    if (tid < 256) x = tanhf(fmaxf(red2[0][tid], red2[1][tid]));
    float m = x;
#pragma unroll
    for (int s = 1; s < 64; s <<= 1) m = fmaxf(m, __shfl_xor(m, s));
    if (ln == 0) scratch[wid] = m;
    __syncthreads();
    float bm = scratch[0];
#pragma unroll
    for (int i = 1; i < 8; i++) bm = fmaxf(bm, scratch[i]);
    float e = (tid < 256) ? expf(x - bm) : 0.f;
    float sm = e;
#pragma unroll
    for (int s = 1; s < 64; s <<= 1) sm += __shfl_xor(sm, s);
    if (ln == 0) scratch[8 + wid] = sm;
    __syncthreads();
    float tot = 0.f;
#pragma unroll
    for (int i = 0; i < 8; i++) tot += scratch[8 + i];
    if (tid < 256) red2[0][tid] = e / tot;   // aq (x-reads of red2 all happened before last barrier)
    __syncthreads();

    // ---- f_w[d] = sum_l aq[l] * E_b[l][d]  (reuse HtS as the reduction buffer) ----
    float* fred = (float*)HtS;               // 16 x 256 floats
    {
        int g = tid >> 5;                    // 0..15 -> l-range [16g, 16g+16)
        int d0 = (tid & 31) << 3;            // 8 d's per thread
        float s0[8] = {0.f, 0.f, 0.f, 0.f, 0.f, 0.f, 0.f, 0.f};
        int lbase = g << 4;
#pragma unroll
        for (int li = 0; li < 16; li++) {
            int l = lbase + li;
            float aql = red2[0][l];
            short8 v = *(const short8*)(Eb + (l << 8) + d0);
#pragma unroll
            for (int jj = 0; jj < 8; jj++)
                s0[jj] += aql * bf2f((unsigned short)v[jj]);
        }
        f32x4 w0, w1;
        w0[0] = s0[0]; w0[1] = s0[1]; w0[2] = s0[2]; w0[3] = s0[3];
        w1[0] = s0[4]; w1[1] = s0[5]; w1[2] = s0[6]; w1[3] = s0[7];
        *(f32x4*)(fred + g * 256 + d0) = w0;
        *(f32x4*)(fred + g * 256 + d0 + 4) = w1;
    }
    __syncthreads();
    if (tid < 256) {
        float f = 0.f;
#pragma unroll
        for (int g2 = 0; g2 < 16; g2++) f += fred[g2 * 256 + tid];
        fw[(b << 8) + tid] = f;
    }
}

// ---------------- Kernel 3: out = f_w @ lin_w^T + lin_b  (fp32 tiled GEMM) ----------------
__global__ __launch_bounds__(256) void k_out(const float* __restrict__ fw,
                                             const float* __restrict__ lw,
                                             const float* __restrict__ lb,
                                             float* __restrict__ out) {
    __shared__ float As[64][65];
    __shared__ float Bs[64][65];
    int tx = threadIdx.x & 15, ty = threadIdx.x >> 4;
    int r0 = blockIdx.y * 64, n0 = blockIdx.x * 64;
    float acc[4][4] = {};
    for (int k0 = 0; k0 < 256; k0 += 64) {
        __syncthreads();
#pragma unroll
        for (int it = 0; it < 16; it++) {
            int idx = it * 256 + threadIdx.x;
            int i = idx >> 6, k = idx & 63;
            As[i][k] = fw[(r0 + i) * 256 + k0 + k];
            int n = n0 + i;
            Bs[k][i] = (n < O_) ? lw[(size_t)n * 256 + k0 + k] : 0.f;
        }
        __syncthreads();
#pragma unroll
        for (int k = 0; k < 64; k++) {
            float a[4], bb[4];
#pragma unroll
            for (int i = 0; i < 4; i++) a[i] = As[ty * 4 + i][k];
#pragma unroll
            for (int j = 0; j < 4; j++) bb[j] = Bs[k][tx * 4 + j];
#pragma unroll
            for (int i = 0; i < 4; i++)
#pragma unroll
                for (int j = 0; j < 4; j++) acc[i][j] += a[i] * bb[j];
        }
    }
#pragma unroll
    for (int i = 0; i < 4; i++)
#pragma unroll
        for (int j = 0; j < 4; j++) {
            int n = n0 + tx * 4 + j;
            if (n < O_) out[(size_t)(r0 + ty * 4 + i) * O_ + n] = acc[i][j] + lb[n];
        }
}

extern "C" void kernel_launch(void* const* d_in, const int* in_sizes, int n_in,
                              void* d_out, int out_size, void* d_ws, size_t ws_size,
                              hipStream_t stream) {
    const int* tok = (const int*)d_in[0];
    const float* emb = (const float*)d_in[1];
    const float* Wb = (const float*)d_in[2];
    const float* lw = (const float*)d_in[3];
    const float* lb = (const float*)d_in[4];
    float* out = (float*)d_out;

    char* ws = (char*)d_ws;
    unsigned short* E   = (unsigned short*)(ws);                // 67,108,864 B
    unsigned short* Wbf = (unsigned short*)(ws + 67108864);     //    131,072 B
    float*          fwp = (float*)(ws + 67239936);              //    524,288 B

    hipLaunchKernelGGL(k_gather, dim3(16384), dim3(256), 0, stream, tok, emb, E);
    hipLaunchKernelGGL(k_wt,     dim3(256),   dim3(256), 0, stream, Wb, Wbf);
    hipLaunchKernelGGL(k_attn,   dim3(512),   dim3(512), 0, stream, E, Wbf, fwp);
    hipLaunchKernelGGL(k_out,    dim3(16, 8), dim3(256), 0, stream, fwp, lw, lb, out);
}